// Round 1
// baseline (1661.031 us; speedup 1.0000x reference)
//
#include <hip/hip_runtime.h>
#include <hip/hip_bf16.h>

// GCN 2-layer forward, fp32 baseline.
// Layout of workspace (floats): h1[N*128] | out1[N*128] | h2[N*2] | dinv[N]
// ~103.6 MB total.

#define D1 128   // D_IN == HIDDEN == 128
#define D2 2     // output classes

// ---------------- degree / dinv ----------------
__global__ void k_deg_init(float* __restrict__ deg, int N) {
    int i = blockIdx.x * 256 + threadIdx.x;
    if (i < N) deg[i] = 1.0f;
}

__global__ void k_deg_acc(const int* __restrict__ dst, float* __restrict__ deg, int E) {
    int e = blockIdx.x * 256 + threadIdx.x;
    if (e < E) atomicAdd(&deg[dst[e]], 1.0f);
}

__global__ void k_dinv(float* __restrict__ deg, int N) {
    int i = blockIdx.x * 256 + threadIdx.x;
    if (i < N) deg[i] = rsqrtf(deg[i]);
}

// ---------------- GEMM1: h1 = x @ W1 ; out1 = h1 * dinv^2 ----------------
// BM=64 rows/block, 256 threads, full K=128 and BN=128 in one pass.
// LDS: Ws 64 KB + Xs 64x132 (pad +4 keeps float4 alignment, kills 4-way read conflicts)
#define BM 64
__global__ __launch_bounds__(256) void k_gemm1(
    const float* __restrict__ x, const float* __restrict__ W1,
    const float* __restrict__ dinv,
    float* __restrict__ h1, float* __restrict__ out1, int N)
{
    __shared__ float Ws[D1 * D1];      // 64 KB
    __shared__ float Xs[BM * 132];     // 33 KB, padded stride 132 (16B-aligned rows)

    const int t = threadIdx.x;
    const int row0 = blockIdx.x * BM;

    // stage W1: 4096 float4, 16 per thread
    const float4* W4 = (const float4*)W1;
    float4* Ws4 = (float4*)Ws;
#pragma unroll
    for (int i = 0; i < 16; ++i) Ws4[t + 256 * i] = W4[t + 256 * i];

    // stage X tile: 2048 float4, 8 per thread
#pragma unroll
    for (int i = 0; i < 8; ++i) {
        int idx = t + 256 * i;            // 0..2047
        int r = idx >> 5, c = idx & 31;   // r: row in tile, c: float4 col
        int row = row0 + r;
        float4 v = make_float4(0.f, 0.f, 0.f, 0.f);
        if (row < N) v = ((const float4*)x)[(size_t)row * 32 + c];
        *(float4*)&Xs[r * 132 + c * 4] = v;   // row stride 132*4=528 B, 16B-aligned
    }
    __syncthreads();

    const int ty = t >> 4;   // 0..15  -> rows ty + 16*i
    const int tx = t & 15;   // 0..15  -> cols tx*8 + j

    float acc[4][8] = {};
#pragma unroll 4
    for (int k = 0; k < D1; ++k) {
        float a0 = Xs[(ty +  0) * 132 + k];
        float a1 = Xs[(ty + 16) * 132 + k];
        float a2 = Xs[(ty + 32) * 132 + k];
        float a3 = Xs[(ty + 48) * 132 + k];
        float4 b0 = *(const float4*)&Ws[k * D1 + tx * 8];
        float4 b1v = *(const float4*)&Ws[k * D1 + tx * 8 + 4];
        float b[8] = {b0.x, b0.y, b0.z, b0.w, b1v.x, b1v.y, b1v.z, b1v.w};
#pragma unroll
        for (int j = 0; j < 8; ++j) {
            acc[0][j] += a0 * b[j];
            acc[1][j] += a1 * b[j];
            acc[2][j] += a2 * b[j];
            acc[3][j] += a3 * b[j];
        }
    }

#pragma unroll
    for (int i = 0; i < 4; ++i) {
        int row = row0 + ty + 16 * i;
        if (row >= N) continue;
        float di = dinv[row];
        float d2 = di * di;
        float* hp = &h1[(size_t)row * D1 + tx * 8];
        float* op = &out1[(size_t)row * D1 + tx * 8];
        float4 v0 = make_float4(acc[i][0], acc[i][1], acc[i][2], acc[i][3]);
        float4 v1 = make_float4(acc[i][4], acc[i][5], acc[i][6], acc[i][7]);
        *(float4*)hp = v0;
        *(float4*)(hp + 4) = v1;
        *(float4*)op = make_float4(v0.x * d2, v0.y * d2, v0.z * d2, v0.w * d2);
        *(float4*)(op + 4) = make_float4(v1.x * d2, v1.y * d2, v1.z * d2, v1.w * d2);
    }
}

// ---------------- scatter layer 1: out1[dst] += h1[src] * (dinv[s]*dinv[d]) ----------------
// 32 lanes per edge, float4 per lane -> coalesced 512 B gather + 4 atomics/lane.
__global__ void k_scatter1(const int* __restrict__ src, const int* __restrict__ dst,
                           const float* __restrict__ dinv, const float* __restrict__ h1,
                           float* __restrict__ out1, int E)
{
    int gid = blockIdx.x * 256 + threadIdx.x;
    int e = gid >> 5;
    if (e >= E) return;
    int f = gid & 31;
    int s = src[e], d = dst[e];
    float w = dinv[s] * dinv[d];
    float4 v = ((const float4*)h1)[(size_t)s * 32 + f];
    float* op = &out1[(size_t)d * D1 + f * 4];
    atomicAdd(op + 0, v.x * w);
    atomicAdd(op + 1, v.y * w);
    atomicAdd(op + 2, v.z * w);
    atomicAdd(op + 3, v.w * w);
}

// ---------------- GEMM2: h2 = relu(out1 + b1) @ W2 ; out = h2*dinv^2 + b2 ----------------
// 32 lanes per row; lane handles 4 features (float4); shfl reduce within 32.
__global__ __launch_bounds__(256) void k_gemm2(
    const float* __restrict__ out1, const float* __restrict__ b1,
    const float* __restrict__ W2, const float* __restrict__ b2,
    const float* __restrict__ dinv,
    float* __restrict__ h2, float* __restrict__ out, int N)
{
    int t = threadIdx.x;
    int half = t >> 5;     // 0..7 rows per block
    int lane = t & 31;
    int row = blockIdx.x * 8 + half;
    if (row >= N) return;

    float4 v  = ((const float4*)out1)[(size_t)row * 32 + lane];
    float4 bb = ((const float4*)b1)[lane];
    float a0 = fmaxf(v.x + bb.x, 0.f);
    float a1 = fmaxf(v.y + bb.y, 0.f);
    float a2 = fmaxf(v.z + bb.z, 0.f);
    float a3 = fmaxf(v.w + bb.w, 0.f);

    // W2 row-major [128][2]; lane needs rows 4*lane .. 4*lane+3
    float4 w01 = ((const float4*)W2)[lane * 2 + 0]; // W2[4l][0..1], W2[4l+1][0..1]
    float4 w23 = ((const float4*)W2)[lane * 2 + 1]; // W2[4l+2][0..1], W2[4l+3][0..1]

    float p0 = a0 * w01.x + a1 * w01.z + a2 * w23.x + a3 * w23.z;
    float p1 = a0 * w01.y + a1 * w01.w + a2 * w23.y + a3 * w23.w;

#pragma unroll
    for (int off = 16; off > 0; off >>= 1) {
        p0 += __shfl_down(p0, off, 32);
        p1 += __shfl_down(p1, off, 32);
    }
    if (lane == 0) {
        float di = dinv[row], d2 = di * di;
        h2[(size_t)row * 2 + 0] = p0;
        h2[(size_t)row * 2 + 1] = p1;
        out[(size_t)row * 2 + 0] = p0 * d2 + b2[0];
        out[(size_t)row * 2 + 1] = p1 * d2 + b2[1];
    }
}

// ---------------- scatter layer 2 (2 floats/edge) ----------------
__global__ void k_scatter2(const int* __restrict__ src, const int* __restrict__ dst,
                           const float* __restrict__ dinv, const float* __restrict__ h2,
                           float* __restrict__ out, int E)
{
    int e = blockIdx.x * 256 + threadIdx.x;
    if (e >= E) return;
    int s = src[e], d = dst[e];
    float w = dinv[s] * dinv[d];
    atomicAdd(&out[(size_t)d * 2 + 0], h2[(size_t)s * 2 + 0] * w);
    atomicAdd(&out[(size_t)d * 2 + 1], h2[(size_t)s * 2 + 1] * w);
}

extern "C" void kernel_launch(void* const* d_in, const int* in_sizes, int n_in,
                              void* d_out, int out_size, void* d_ws, size_t ws_size,
                              hipStream_t stream)
{
    const float* x  = (const float*)d_in[0];
    const int*   ei = (const int*)d_in[1];
    const float* W1 = (const float*)d_in[2];
    const float* b1 = (const float*)d_in[3];
    const float* W2 = (const float*)d_in[4];
    const float* b2 = (const float*)d_in[5];
    float* out = (float*)d_out;

    const int N = in_sizes[0] / D1;
    const int E = in_sizes[1] / 2;
    const int* src = ei;
    const int* dst = ei + E;

    float* h1   = (float*)d_ws;                 // N*128
    float* out1 = h1 + (size_t)N * D1;          // N*128
    float* h2   = out1 + (size_t)N * D1;        // N*2
    float* dinv = h2 + (size_t)N * 2;           // N

    // degree -> dinv
    k_deg_init<<<(N + 255) / 256, 256, 0, stream>>>(dinv, N);
    k_deg_acc <<<(E + 255) / 256, 256, 0, stream>>>(dst, dinv, E);
    k_dinv    <<<(N + 255) / 256, 256, 0, stream>>>(dinv, N);

    // layer 1
    k_gemm1<<<(N + BM - 1) / BM, 256, 0, stream>>>(x, W1, dinv, h1, out1, N);
    {
        long total = (long)E * 32;
        k_scatter1<<<(int)((total + 255) / 256), 256, 0, stream>>>(src, dst, dinv, h1, out1, E);
    }

    // layer 2 (relu + bias fused into the GEMM2 read)
    k_gemm2<<<(N + 7) / 8, 256, 0, stream>>>(out1, b1, W2, b2, dinv, h2, out, N);
    k_scatter2<<<(E + 255) / 256, 256, 0, stream>>>(src, dst, dinv, h2, out, E);
}

// Round 2
// 340.610 us; speedup vs baseline: 4.8766x; 4.8766x over previous
//
#include <hip/hip_runtime.h>
#include <hip/hip_bf16.h>

// GCN 2-layer forward. CSR-pull aggregation (no float atomics).
// ws layout (4B units): h1[128N] | out1[128N] | h2[2N] | dinv[N] | cnt(->cursor)[N]
//                       | rowptr[N+2] | bsum[256] | boff[256] | epack[2E] (int2)

#define D1 128

// ---------------- CSR build ----------------
__global__ void k_zero(int* __restrict__ p, int n) {
    int i = blockIdx.x * 256 + threadIdx.x;
    if (i < n) p[i] = 0;
}

__global__ void k_hist(const int* __restrict__ dst, int* __restrict__ cnt, int E) {
    int e = blockIdx.x * 256 + threadIdx.x;
    if (e < E) atomicAdd(&cnt[dst[e]], 1);
}

__global__ void k_dinv(const int* __restrict__ cnt, float* __restrict__ dinv, int N) {
    int i = blockIdx.x * 256 + threadIdx.x;
    if (i < N) dinv[i] = rsqrtf(1.0f + (float)cnt[i]);   // deg includes self-loop
}

// block-level scan: 256 threads x 4 elems = 1024/block
__global__ __launch_bounds__(256) void k_scan1(const int* __restrict__ cnt,
                                               int* __restrict__ rowptr,
                                               int* __restrict__ bsum, int N) {
    __shared__ int sd[256];
    int t = threadIdx.x, b = blockIdx.x;
    int base = b * 1024 + t * 4;
    int v[4], tsum = 0;
#pragma unroll
    for (int i = 0; i < 4; ++i) { v[i] = (base + i < N) ? cnt[base + i] : 0; tsum += v[i]; }
    sd[t] = tsum;
    __syncthreads();
    for (int off = 1; off < 256; off <<= 1) {
        int x = (t >= off) ? sd[t - off] : 0;
        __syncthreads();
        sd[t] += x;
        __syncthreads();
    }
    int run = sd[t] - tsum;   // exclusive across threads
#pragma unroll
    for (int i = 0; i < 4; ++i) {
        if (base + i < N) rowptr[base + i] = run;
        run += v[i];
    }
    if (t == 255) bsum[b] = sd[255];
}

__global__ void k_scan2(const int* __restrict__ bsum, int* __restrict__ boff, int nb) {
    __shared__ int sd[256];
    int t = threadIdx.x;
    int v = (t < nb) ? bsum[t] : 0;
    sd[t] = v;
    __syncthreads();
    for (int off = 1; off < 256; off <<= 1) {
        int x = (t >= off) ? sd[t - off] : 0;
        __syncthreads();
        sd[t] += x;
        __syncthreads();
    }
    if (t < nb) boff[t] = sd[t] - v;
}

__global__ void k_scan3(int* __restrict__ rowptr, int* __restrict__ cursor,
                        const int* __restrict__ boff, int N, int E) {
    int i = blockIdx.x * 256 + threadIdx.x;
    if (i < N) {
        int r = rowptr[i] + boff[i >> 10];
        rowptr[i] = r;
        cursor[i] = r;
    }
    if (i == 0) rowptr[N] = E;
}

__global__ void k_fill(const int* __restrict__ src, const int* __restrict__ dst,
                       const float* __restrict__ dinv, int* __restrict__ cursor,
                       int2* __restrict__ epack, int E) {
    int e = blockIdx.x * 256 + threadIdx.x;
    if (e >= E) return;
    int s = src[e], d = dst[e];
    float w = dinv[s] * dinv[d];
    int pos = atomicAdd(&cursor[d], 1);
    epack[pos] = make_int2(s, __float_as_int(w));
}

// ---------------- GEMM1: h1 = x @ W1 ----------------
#define BM 64
__global__ __launch_bounds__(256) void k_gemm1(
    const float* __restrict__ x, const float* __restrict__ W1,
    float* __restrict__ h1, int N)
{
    __shared__ float Ws[D1 * D1];      // 64 KB
    __shared__ float Xs[BM * 132];     // padded stride 132

    const int t = threadIdx.x;
    const int row0 = blockIdx.x * BM;

    const float4* W4 = (const float4*)W1;
    float4* Ws4 = (float4*)Ws;
#pragma unroll
    for (int i = 0; i < 16; ++i) Ws4[t + 256 * i] = W4[t + 256 * i];

#pragma unroll
    for (int i = 0; i < 8; ++i) {
        int idx = t + 256 * i;
        int r = idx >> 5, c = idx & 31;
        int row = row0 + r;
        float4 v = make_float4(0.f, 0.f, 0.f, 0.f);
        if (row < N) v = ((const float4*)x)[(size_t)row * 32 + c];
        *(float4*)&Xs[r * 132 + c * 4] = v;
    }
    __syncthreads();

    const int ty = t >> 4;
    const int tx = t & 15;

    float acc[4][8] = {};
#pragma unroll 4
    for (int k = 0; k < D1; ++k) {
        float a0 = Xs[(ty +  0) * 132 + k];
        float a1 = Xs[(ty + 16) * 132 + k];
        float a2 = Xs[(ty + 32) * 132 + k];
        float a3 = Xs[(ty + 48) * 132 + k];
        float4 b0 = *(const float4*)&Ws[k * D1 + tx * 8];
        float4 b1v = *(const float4*)&Ws[k * D1 + tx * 8 + 4];
        float b[8] = {b0.x, b0.y, b0.z, b0.w, b1v.x, b1v.y, b1v.z, b1v.w};
#pragma unroll
        for (int j = 0; j < 8; ++j) {
            acc[0][j] += a0 * b[j];
            acc[1][j] += a1 * b[j];
            acc[2][j] += a2 * b[j];
            acc[3][j] += a3 * b[j];
        }
    }

#pragma unroll
    for (int i = 0; i < 4; ++i) {
        int row = row0 + ty + 16 * i;
        if (row >= N) continue;
        float* hp = &h1[(size_t)row * D1 + tx * 8];
        *(float4*)hp = make_float4(acc[i][0], acc[i][1], acc[i][2], acc[i][3]);
        *(float4*)(hp + 4) = make_float4(acc[i][4], acc[i][5], acc[i][6], acc[i][7]);
    }
}

// ---------------- gather layer 1 (pull, no atomics) ----------------
// 32 lanes per node, float4/lane. out1[d] = h1[d]*dinv^2 + sum_e h1[src]*w
__global__ __launch_bounds__(256) void k_gather1(
    const int* __restrict__ rowptr, const int2* __restrict__ epack,
    const float* __restrict__ dinv, const float* __restrict__ h1,
    float* __restrict__ out1, int N)
{
    int gid = blockIdx.x * 256 + threadIdx.x;
    int node = gid >> 5;
    if (node >= N) return;
    int lane = gid & 31;

    float di = dinv[node];
    float d2 = di * di;
    float4 acc = ((const float4*)h1)[(size_t)node * 32 + lane];
    acc.x *= d2; acc.y *= d2; acc.z *= d2; acc.w *= d2;

    int beg = rowptr[node], end = rowptr[node + 1];
    for (int e = beg; e < end; ++e) {
        int2 p = epack[e];                    // broadcast across 32 lanes
        float w = __int_as_float(p.y);
        float4 v = ((const float4*)h1)[(size_t)p.x * 32 + lane];
        acc.x += v.x * w; acc.y += v.y * w; acc.z += v.z * w; acc.w += v.w * w;
    }
    ((float4*)out1)[(size_t)node * 32 + lane] = acc;
}

// ---------------- GEMM2: h2 = relu(out1 + b1) @ W2 ----------------
__global__ __launch_bounds__(256) void k_gemm2(
    const float* __restrict__ out1, const float* __restrict__ b1,
    const float* __restrict__ W2, float* __restrict__ h2, int N)
{
    int t = threadIdx.x;
    int grp = t >> 5;
    int lane = t & 31;
    int row = blockIdx.x * 8 + grp;
    if (row >= N) return;

    float4 v  = ((const float4*)out1)[(size_t)row * 32 + lane];
    float4 bb = ((const float4*)b1)[lane];
    float a0 = fmaxf(v.x + bb.x, 0.f);
    float a1 = fmaxf(v.y + bb.y, 0.f);
    float a2 = fmaxf(v.z + bb.z, 0.f);
    float a3 = fmaxf(v.w + bb.w, 0.f);

    float4 w01 = ((const float4*)W2)[lane * 2 + 0];
    float4 w23 = ((const float4*)W2)[lane * 2 + 1];

    float p0 = a0 * w01.x + a1 * w01.z + a2 * w23.x + a3 * w23.z;
    float p1 = a0 * w01.y + a1 * w01.w + a2 * w23.y + a3 * w23.w;

#pragma unroll
    for (int off = 16; off > 0; off >>= 1) {
        p0 += __shfl_down(p0, off, 32);
        p1 += __shfl_down(p1, off, 32);
    }
    if (lane == 0) {
        h2[(size_t)row * 2 + 0] = p0;
        h2[(size_t)row * 2 + 1] = p1;
    }
}

// ---------------- gather layer 2 (pull) ----------------
__global__ void k_gather2(const int* __restrict__ rowptr, const int2* __restrict__ epack,
                          const float* __restrict__ h2, const float* __restrict__ dinv,
                          const float* __restrict__ b2, float* __restrict__ out, int N)
{
    int i = blockIdx.x * 256 + threadIdx.x;
    if (i >= N) return;
    float di = dinv[i], d2 = di * di;
    float2 h = ((const float2*)h2)[i];
    float o0 = h.x * d2, o1 = h.y * d2;
    int beg = rowptr[i], end = rowptr[i + 1];
    for (int e = beg; e < end; ++e) {
        int2 p = epack[e];
        float w = __int_as_float(p.y);
        float2 v = ((const float2*)h2)[p.x];
        o0 += v.x * w; o1 += v.y * w;
    }
    ((float2*)out)[i] = make_float2(o0 + b2[0], o1 + b2[1]);
}

extern "C" void kernel_launch(void* const* d_in, const int* in_sizes, int n_in,
                              void* d_out, int out_size, void* d_ws, size_t ws_size,
                              hipStream_t stream)
{
    const float* x  = (const float*)d_in[0];
    const int*   ei = (const int*)d_in[1];
    const float* W1 = (const float*)d_in[2];
    const float* b1 = (const float*)d_in[3];
    const float* W2 = (const float*)d_in[4];
    const float* b2 = (const float*)d_in[5];
    float* out = (float*)d_out;

    const int N = in_sizes[0] / D1;
    const int E = in_sizes[1] / 2;
    const int* src = ei;
    const int* dst = ei + E;

    float* h1     = (float*)d_ws;                    // 128N
    float* out1   = h1 + (size_t)N * D1;             // 128N
    float* h2     = out1 + (size_t)N * D1;           // 2N
    float* dinv   = h2 + (size_t)N * 2;              // N
    int*   cnt    = (int*)(dinv + N);                // N   (reused as cursor)
    int*   rowptr = cnt + N;                         // N+2 (pad to even)
    int*   bsum   = rowptr + N + 2;                  // 256
    int*   boff   = bsum + 256;                      // 256
    int2*  epack  = (int2*)(boff + 256);             // E int2 (8B aligned)

    const int nb = (N + 1023) >> 10;                 // blocks for scan1 (<=256)

    // CSR build + dinv
    k_zero <<<(N + 255) / 256, 256, 0, stream>>>(cnt, N);
    k_hist <<<(E + 255) / 256, 256, 0, stream>>>(dst, cnt, E);
    k_dinv <<<(N + 255) / 256, 256, 0, stream>>>(cnt, dinv, N);
    k_scan1<<<nb, 256, 0, stream>>>(cnt, rowptr, bsum, N);
    k_scan2<<<1, 256, 0, stream>>>(bsum, boff, nb);
    k_scan3<<<(N + 255) / 256, 256, 0, stream>>>(rowptr, cnt, boff, N, E); // cnt = cursor
    k_fill <<<(E + 255) / 256, 256, 0, stream>>>(src, dst, dinv, cnt, epack, E);

    // layer 1
    k_gemm1  <<<(N + BM - 1) / BM, 256, 0, stream>>>(x, W1, h1, N);
    k_gather1<<<(N * 32 + 255) / 256, 256, 0, stream>>>(rowptr, epack, dinv, h1, out1, N);

    // layer 2
    k_gemm2  <<<(N + 7) / 8, 256, 0, stream>>>(out1, b1, W2, h2, N);
    k_gather2<<<(N + 255) / 256, 256, 0, stream>>>(rowptr, epack, h2, dinv, b2, out, N);
}

// Round 3
// 302.731 us; speedup vs baseline: 5.4868x; 1.1251x over previous
//
#include <hip/hip_runtime.h>
#include <hip/hip_bf16.h>

// GCN 2-layer forward. CSR-pull aggregation, fused agg1+relu+GEMM2.
// ws layout (4B units): h1[128N] | h2[2N] | dinv[N] | cnt(->cursor)[N]
//                       | rowptr[N+2] | bsum[256] | boff[256] | epack[2E] (int2)

#define D1 128

// ---------------- CSR build ----------------
__global__ void k_zero(int* __restrict__ p, int n) {
    int i = blockIdx.x * 256 + threadIdx.x;
    if (i < n) p[i] = 0;
}

__global__ void k_hist(const int* __restrict__ dst, int* __restrict__ cnt, int E) {
    int e = blockIdx.x * 256 + threadIdx.x;
    if (e < E) atomicAdd(&cnt[dst[e]], 1);
}

__global__ void k_dinv(const int* __restrict__ cnt, float* __restrict__ dinv, int N) {
    int i = blockIdx.x * 256 + threadIdx.x;
    if (i < N) dinv[i] = rsqrtf(1.0f + (float)cnt[i]);   // deg includes self-loop
}

// block-level scan: 256 threads x 4 elems = 1024/block
__global__ __launch_bounds__(256) void k_scan1(const int* __restrict__ cnt,
                                               int* __restrict__ rowptr,
                                               int* __restrict__ bsum, int N) {
    __shared__ int sd[256];
    int t = threadIdx.x, b = blockIdx.x;
    int base = b * 1024 + t * 4;
    int v[4], tsum = 0;
#pragma unroll
    for (int i = 0; i < 4; ++i) { v[i] = (base + i < N) ? cnt[base + i] : 0; tsum += v[i]; }
    sd[t] = tsum;
    __syncthreads();
    for (int off = 1; off < 256; off <<= 1) {
        int x = (t >= off) ? sd[t - off] : 0;
        __syncthreads();
        sd[t] += x;
        __syncthreads();
    }
    int run = sd[t] - tsum;
#pragma unroll
    for (int i = 0; i < 4; ++i) {
        if (base + i < N) rowptr[base + i] = run;
        run += v[i];
    }
    if (t == 255) bsum[b] = sd[255];
}

__global__ void k_scan2(const int* __restrict__ bsum, int* __restrict__ boff, int nb) {
    __shared__ int sd[256];
    int t = threadIdx.x;
    int v = (t < nb) ? bsum[t] : 0;
    sd[t] = v;
    __syncthreads();
    for (int off = 1; off < 256; off <<= 1) {
        int x = (t >= off) ? sd[t - off] : 0;
        __syncthreads();
        sd[t] += x;
        __syncthreads();
    }
    if (t < nb) boff[t] = sd[t] - v;
}

__global__ void k_scan3(int* __restrict__ rowptr, int* __restrict__ cursor,
                        const int* __restrict__ boff, int N, int E) {
    int i = blockIdx.x * 256 + threadIdx.x;
    if (i < N) {
        int r = rowptr[i] + boff[i >> 10];
        rowptr[i] = r;
        cursor[i] = r;
    }
    if (i == 0) rowptr[N] = E;
}

__global__ void k_fill(const int* __restrict__ src, const int* __restrict__ dst,
                       const float* __restrict__ dinv, int* __restrict__ cursor,
                       int2* __restrict__ epack, int E) {
    int e = blockIdx.x * 256 + threadIdx.x;
    if (e >= E) return;
    int s = src[e], d = dst[e];
    float w = dinv[s] * dinv[d];
    int pos = atomicAdd(&cursor[d], 1);
    epack[pos] = make_int2(s, __float_as_int(w));
}

// ---------------- GEMM1: h1 = x @ W1 ----------------
// 256 threads, BM=64 rows, K chunked by 32. acc 4x8 per thread.
// Thread (ty=t>>4, tx=t&15): rows {ty+16i}, cols {tx*4+j, 64+tx*4+j}.
// B-reads are consecutive float4s across lanes -> 2-way bank alias (free).
#define BM 64
#define BK 32
__global__ __launch_bounds__(256) void k_gemm1(
    const float* __restrict__ x, const float* __restrict__ W1,
    float* __restrict__ h1, int N)
{
    __shared__ float Xs[BM][BK + 8];   // stride 40 words (160 B, 16B-aligned)
    __shared__ float Ws[BK][D1];       // 16 KB

    const int t = threadIdx.x;
    const int row0 = blockIdx.x * BM;
    const int ty = t >> 4;
    const int tx = t & 15;

    float acc[4][8] = {};

    for (int k0 = 0; k0 < D1; k0 += BK) {
        // stage X chunk: 64 rows x 8 float4 = 512 loads, 2/thread
#pragma unroll
        for (int i = 0; i < 2; ++i) {
            int idx = t + 256 * i;
            int r = idx >> 3, c = idx & 7;
            int row = row0 + r;
            float4 v = make_float4(0.f, 0.f, 0.f, 0.f);
            if (row < N) v = ((const float4*)x)[(size_t)row * 32 + (k0 >> 2) + c];
            *(float4*)&Xs[r][c * 4] = v;
        }
        // stage W chunk: 32 rows x 32 float4 = 1024 loads, 4/thread
#pragma unroll
        for (int i = 0; i < 4; ++i) {
            int idx = t + 256 * i;
            int kk = idx >> 5, c = idx & 31;
            *(float4*)&Ws[kk][c * 4] = ((const float4*)W1)[(size_t)(k0 + kk) * 32 + c];
        }
        __syncthreads();

#pragma unroll 8
        for (int kk = 0; kk < BK; ++kk) {
            float a0 = Xs[ty +  0][kk];
            float a1 = Xs[ty + 16][kk];
            float a2 = Xs[ty + 32][kk];
            float a3 = Xs[ty + 48][kk];
            float4 b0 = *(const float4*)&Ws[kk][tx * 4];
            float4 b1v = *(const float4*)&Ws[kk][64 + tx * 4];
            float b[8] = {b0.x, b0.y, b0.z, b0.w, b1v.x, b1v.y, b1v.z, b1v.w};
#pragma unroll
            for (int j = 0; j < 8; ++j) {
                acc[0][j] += a0 * b[j];
                acc[1][j] += a1 * b[j];
                acc[2][j] += a2 * b[j];
                acc[3][j] += a3 * b[j];
            }
        }
        __syncthreads();
    }

#pragma unroll
    for (int i = 0; i < 4; ++i) {
        int row = row0 + ty + 16 * i;
        if (row >= N) continue;
        float* hp = &h1[(size_t)row * D1];
        *(float4*)(hp + tx * 4)      = make_float4(acc[i][0], acc[i][1], acc[i][2], acc[i][3]);
        *(float4*)(hp + 64 + tx * 4) = make_float4(acc[i][4], acc[i][5], acc[i][6], acc[i][7]);
    }
}

// ---------------- fused: agg(layer1) + relu + bias + GEMM2 ----------------
// 32 lanes/node. Gathers h1 rows, no out1 materialization.
__global__ __launch_bounds__(256) void k_agg1_gemm2(
    const int* __restrict__ rowptr, const int2* __restrict__ epack,
    const float* __restrict__ dinv, const float* __restrict__ h1,
    const float* __restrict__ b1, const float* __restrict__ W2,
    float* __restrict__ h2, int N)
{
    int gid = blockIdx.x * 256 + threadIdx.x;
    int node = gid >> 5;
    if (node >= N) return;
    int lane = gid & 31;

    float di = dinv[node];
    float d2 = di * di;
    float4 acc = ((const float4*)h1)[(size_t)node * 32 + lane];
    acc.x *= d2; acc.y *= d2; acc.z *= d2; acc.w *= d2;

    int beg = rowptr[node], end = rowptr[node + 1];
    for (int e = beg; e < end; ++e) {
        int2 p = epack[e];
        float w = __int_as_float(p.y);
        float4 v = ((const float4*)h1)[(size_t)p.x * 32 + lane];
        acc.x += v.x * w; acc.y += v.y * w; acc.z += v.z * w; acc.w += v.w * w;
    }

    // relu + bias
    float4 bb = ((const float4*)b1)[lane];
    float a0 = fmaxf(acc.x + bb.x, 0.f);
    float a1 = fmaxf(acc.y + bb.y, 0.f);
    float a2 = fmaxf(acc.z + bb.z, 0.f);
    float a3 = fmaxf(acc.w + bb.w, 0.f);

    // W2 [128][2]; lane covers rows 4*lane..4*lane+3
    float4 w01 = ((const float4*)W2)[lane * 2 + 0];
    float4 w23 = ((const float4*)W2)[lane * 2 + 1];

    float p0 = a0 * w01.x + a1 * w01.z + a2 * w23.x + a3 * w23.z;
    float p1 = a0 * w01.y + a1 * w01.w + a2 * w23.y + a3 * w23.w;

#pragma unroll
    for (int off = 16; off > 0; off >>= 1) {
        p0 += __shfl_down(p0, off, 32);
        p1 += __shfl_down(p1, off, 32);
    }
    if (lane == 0) {
        h2[(size_t)node * 2 + 0] = p0;
        h2[(size_t)node * 2 + 1] = p1;
    }
}

// ---------------- gather layer 2 (pull) ----------------
__global__ void k_gather2(const int* __restrict__ rowptr, const int2* __restrict__ epack,
                          const float* __restrict__ h2, const float* __restrict__ dinv,
                          const float* __restrict__ b2, float* __restrict__ out, int N)
{
    int i = blockIdx.x * 256 + threadIdx.x;
    if (i >= N) return;
    float di = dinv[i], d2 = di * di;
    float2 h = ((const float2*)h2)[i];
    float o0 = h.x * d2, o1 = h.y * d2;
    int beg = rowptr[i], end = rowptr[i + 1];
    for (int e = beg; e < end; ++e) {
        int2 p = epack[e];
        float w = __int_as_float(p.y);
        float2 v = ((const float2*)h2)[p.x];
        o0 += v.x * w; o1 += v.y * w;
    }
    ((float2*)out)[i] = make_float2(o0 + b2[0], o1 + b2[1]);
}

extern "C" void kernel_launch(void* const* d_in, const int* in_sizes, int n_in,
                              void* d_out, int out_size, void* d_ws, size_t ws_size,
                              hipStream_t stream)
{
    const float* x  = (const float*)d_in[0];
    const int*   ei = (const int*)d_in[1];
    const float* W1 = (const float*)d_in[2];
    const float* b1 = (const float*)d_in[3];
    const float* W2 = (const float*)d_in[4];
    const float* b2 = (const float*)d_in[5];
    float* out = (float*)d_out;

    const int N = in_sizes[0] / D1;
    const int E = in_sizes[1] / 2;
    const int* src = ei;
    const int* dst = ei + E;

    float* h1     = (float*)d_ws;                    // 128N
    float* h2     = h1 + (size_t)N * D1;             // 2N
    float* dinv   = h2 + (size_t)N * 2;              // N
    int*   cnt    = (int*)(dinv + N);                // N (reused as cursor)
    int*   rowptr = cnt + N;                         // N+2
    int*   bsum   = rowptr + N + 2;                  // 256
    int*   boff   = bsum + 256;                      // 256
    int2*  epack  = (int2*)(boff + 256);             // E int2

    const int nb = (N + 1023) >> 10;

    // CSR build + dinv
    k_zero <<<(N + 255) / 256, 256, 0, stream>>>(cnt, N);
    k_hist <<<(E + 255) / 256, 256, 0, stream>>>(dst, cnt, E);
    k_dinv <<<(N + 255) / 256, 256, 0, stream>>>(cnt, dinv, N);
    k_scan1<<<nb, 256, 0, stream>>>(cnt, rowptr, bsum, N);
    k_scan2<<<1, 256, 0, stream>>>(bsum, boff, nb);
    k_scan3<<<(N + 255) / 256, 256, 0, stream>>>(rowptr, cnt, boff, N, E);
    k_fill <<<(E + 255) / 256, 256, 0, stream>>>(src, dst, dinv, cnt, epack, E);

    // layer 1 GEMM
    k_gemm1<<<(N + BM - 1) / BM, 256, 0, stream>>>(x, W1, h1, N);

    // fused agg1 + relu + bias + GEMM2
    k_agg1_gemm2<<<(N * 32 + 255) / 256, 256, 0, stream>>>(rowptr, epack, dinv, h1, b1, W2, h2, N);

    // layer 2 aggregation
    k_gather2<<<(N + 255) / 256, 256, 0, stream>>>(rowptr, epack, h2, dinv, b2, out, N);
}

// Round 4
// 263.623 us; speedup vs baseline: 6.3008x; 1.1483x over previous
//
#include <hip/hip_runtime.h>
#include <hip/hip_bf16.h>

// GCN 2-layer forward. CSR-pull aggregation, bf16 h1, MFMA GEMM1, fused agg1+GEMM2.
// ws layout (bytes): h1 bf16[N*128] | W1t bf16[128*128] | h2 f32[2N] | dinv f32[N]
//                    | cnt i32[N] | rowptr i32[N+2] | bsum[256] | boff[256] | epack int2[E]

#define D1 128

typedef __attribute__((ext_vector_type(8))) short short8;
typedef __attribute__((ext_vector_type(4))) float floatx4;

__device__ __forceinline__ unsigned short f2bf(float f) {
    unsigned u = __float_as_uint(f);
    u += 0x7fff + ((u >> 16) & 1);         // RNE to bf16
    return (unsigned short)(u >> 16);
}
__device__ __forceinline__ float bflo(unsigned u) { return __uint_as_float(u << 16); }
__device__ __forceinline__ float bfhi(unsigned u) { return __uint_as_float(u & 0xffff0000u); }

// ---------------- CSR build ----------------
__global__ void k_zero(int* __restrict__ p, int n) {
    int i = blockIdx.x * 256 + threadIdx.x;
    if (i < n) p[i] = 0;
}

__global__ void k_hist(const int* __restrict__ dst, int* __restrict__ cnt, int E) {
    int e = blockIdx.x * 256 + threadIdx.x;
    if (e < E) atomicAdd(&cnt[dst[e]], 1);
}

// scan over 1024/block; also emits dinv = rsqrt(1+deg)
__global__ __launch_bounds__(256) void k_scan1(const int* __restrict__ cnt,
                                               float* __restrict__ dinv,
                                               int* __restrict__ rowptr,
                                               int* __restrict__ bsum, int N) {
    __shared__ int sd[256];
    int t = threadIdx.x, b = blockIdx.x;
    int base = b * 1024 + t * 4;
    int v[4], tsum = 0;
#pragma unroll
    for (int i = 0; i < 4; ++i) {
        v[i] = (base + i < N) ? cnt[base + i] : 0;
        if (base + i < N) dinv[base + i] = rsqrtf(1.0f + (float)v[i]);
        tsum += v[i];
    }
    sd[t] = tsum;
    __syncthreads();
    for (int off = 1; off < 256; off <<= 1) {
        int x = (t >= off) ? sd[t - off] : 0;
        __syncthreads();
        sd[t] += x;
        __syncthreads();
    }
    int run = sd[t] - tsum;
#pragma unroll
    for (int i = 0; i < 4; ++i) {
        if (base + i < N) rowptr[base + i] = run;
        run += v[i];
    }
    if (t == 255) bsum[b] = sd[255];
}

__global__ void k_scan2(const int* __restrict__ bsum, int* __restrict__ boff, int nb) {
    __shared__ int sd[256];
    int t = threadIdx.x;
    int v = (t < nb) ? bsum[t] : 0;
    sd[t] = v;
    __syncthreads();
    for (int off = 1; off < 256; off <<= 1) {
        int x = (t >= off) ? sd[t - off] : 0;
        __syncthreads();
        sd[t] += x;
        __syncthreads();
    }
    if (t < nb) boff[t] = sd[t] - v;
}

__global__ void k_scan3(int* __restrict__ rowptr, int* __restrict__ cursor,
                        const int* __restrict__ boff, int N, int E) {
    int i = blockIdx.x * 256 + threadIdx.x;
    if (i < N) {
        int r = rowptr[i] + boff[i >> 10];
        rowptr[i] = r;
        cursor[i] = r;
    }
    if (i == 0) rowptr[N] = E;
}

__global__ void k_fill(const int* __restrict__ src, const int* __restrict__ dst,
                       const float* __restrict__ dinv, int* __restrict__ cursor,
                       int2* __restrict__ epack, int E) {
    int e = blockIdx.x * 256 + threadIdx.x;
    if (e >= E) return;
    int s = src[e], d = dst[e];
    float w = dinv[s] * dinv[d];
    int pos = atomicAdd(&cursor[d], 1);
    epack[pos] = make_int2(s, __float_as_int(w));
}

// ---------------- W1 -> W1^T bf16 (once per call, 16384 elems) ----------------
__global__ void k_w1cvt(const float* __restrict__ W1, unsigned short* __restrict__ W1t) {
    int i = blockIdx.x * 256 + threadIdx.x;
    int c = i >> 7, k = i & 127;
    W1t[c * D1 + k] = f2bf(W1[k * D1 + c]);
}

// ---------------- GEMM1 (MFMA): h1 = bf16(x) @ bf16(W1), bf16 out ----------------
// 256 thr = 4 waves; block = 64 rows x 128 cols; K=128 in 4 steps of 32.
// LDS rows padded to 136 bf16 (272 B, bank-stride 4) -> b128 frag reads at conflict floor.
#define BMM 64
__global__ __launch_bounds__(256) void k_gemm1(
    const float* __restrict__ x, const unsigned short* __restrict__ W1t,
    unsigned short* __restrict__ h1, int N)
{
    __shared__ unsigned short Xs[BMM][136];   // 17.0 KB
    __shared__ unsigned short Ws[D1][136];    // 34.0 KB  (Ws[col][k])

    const int t = threadIdx.x;
    const int row0 = blockIdx.x * BMM;

    // stage W1t (bf16, already transposed): 128 rows x 16 chunks of 8
#pragma unroll
    for (int i = 0; i < 8; ++i) {
        int idx = t + 256 * i;
        int r = idx >> 4, c8 = idx & 15;
        short8 v = ((const short8*)W1t)[r * 16 + c8];
        *(short8*)&Ws[r][c8 * 8] = v;
    }
    // stage X tile, fp32 -> bf16: 64 rows x 16 chunks of 8
#pragma unroll
    for (int i = 0; i < 4; ++i) {
        int idx = t + 256 * i;
        int r = idx >> 4, c8 = idx & 15;
        int row = row0 + r;
        short8 v8 = (short8)0;
        if (row < N) {
            const float* p = x + (size_t)row * D1 + c8 * 8;
            float4 f0 = *(const float4*)p;
            float4 f1 = *(const float4*)(p + 4);
            v8[0] = (short)f2bf(f0.x); v8[1] = (short)f2bf(f0.y);
            v8[2] = (short)f2bf(f0.z); v8[3] = (short)f2bf(f0.w);
            v8[4] = (short)f2bf(f1.x); v8[5] = (short)f2bf(f1.y);
            v8[6] = (short)f2bf(f1.z); v8[7] = (short)f2bf(f1.w);
        }
        *(short8*)&Xs[r][c8 * 8] = v8;
    }
    __syncthreads();

    const int w = t >> 6;          // wave -> rows 16w..16w+15
    const int l = t & 63;
    const int m = l & 15;          // A row / B col within tile
    const int q = l >> 4;          // quad -> k = q*8 + j

    floatx4 acc[8];
#pragma unroll
    for (int c = 0; c < 8; ++c) acc[c] = (floatx4)0.0f;

#pragma unroll
    for (int ks = 0; ks < 4; ++ks) {
        short8 a = *(const short8*)&Xs[16 * w + m][ks * 32 + q * 8];
#pragma unroll
        for (int c = 0; c < 8; ++c) {
            short8 b = *(const short8*)&Ws[c * 16 + m][ks * 32 + q * 8];
            acc[c] = __builtin_amdgcn_mfma_f32_16x16x32_bf16(a, b, acc[c], 0, 0, 0);
        }
    }

    // epilogue: D[row=q*4+r][col=c*16+m], store bf16
#pragma unroll
    for (int c = 0; c < 8; ++c) {
#pragma unroll
        for (int r = 0; r < 4; ++r) {
            int row = row0 + 16 * w + q * 4 + r;
            if (row < N) h1[(size_t)row * D1 + c * 16 + m] = f2bf(acc[c][r]);
        }
    }
}

// ---------------- fused: agg(layer1, bf16 gather) + relu + bias + GEMM2 ----------------
// 32 lanes/node, lane covers features 4*lane..4*lane+3 (one uint2 = 4 bf16).
__global__ __launch_bounds__(256) void k_agg1_gemm2(
    const int* __restrict__ rowptr, const int2* __restrict__ epack,
    const float* __restrict__ dinv, const unsigned short* __restrict__ h1,
    const float* __restrict__ b1, const float* __restrict__ W2,
    float* __restrict__ h2, int N)
{
    int gid = blockIdx.x * 256 + threadIdx.x;
    int node = gid >> 5;
    if (node >= N) return;
    int lane = gid & 31;

    const uint2* h1v = (const uint2*)h1;   // 32 uint2 per row

    float di = dinv[node];
    float d2 = di * di;
    uint2 u = h1v[(size_t)node * 32 + lane];
    float a0 = bflo(u.x) * d2, a1 = bfhi(u.x) * d2;
    float a2 = bflo(u.y) * d2, a3 = bfhi(u.y) * d2;

    int beg = rowptr[node], end = rowptr[node + 1];
    for (int e = beg; e < end; ++e) {
        int2 p = epack[e];                         // broadcast
        float w = __int_as_float(p.y);
        uint2 v = h1v[(size_t)p.x * 32 + lane];    // 256 B coalesced gather
        a0 += bflo(v.x) * w; a1 += bfhi(v.x) * w;
        a2 += bflo(v.y) * w; a3 += bfhi(v.y) * w;
    }

    // relu + bias
    float4 bb = ((const float4*)b1)[lane];
    a0 = fmaxf(a0 + bb.x, 0.f);
    a1 = fmaxf(a1 + bb.y, 0.f);
    a2 = fmaxf(a2 + bb.z, 0.f);
    a3 = fmaxf(a3 + bb.w, 0.f);

    // W2 [128][2]; lane covers rows 4*lane..4*lane+3
    float4 w01 = ((const float4*)W2)[lane * 2 + 0];
    float4 w23 = ((const float4*)W2)[lane * 2 + 1];

    float p0 = a0 * w01.x + a1 * w01.z + a2 * w23.x + a3 * w23.z;
    float p1 = a0 * w01.y + a1 * w01.w + a2 * w23.y + a3 * w23.w;

#pragma unroll
    for (int off = 16; off > 0; off >>= 1) {
        p0 += __shfl_down(p0, off, 32);
        p1 += __shfl_down(p1, off, 32);
    }
    if (lane == 0) {
        h2[(size_t)node * 2 + 0] = p0;
        h2[(size_t)node * 2 + 1] = p1;
    }
}

// ---------------- gather layer 2 (pull) ----------------
__global__ void k_gather2(const int* __restrict__ rowptr, const int2* __restrict__ epack,
                          const float* __restrict__ h2, const float* __restrict__ dinv,
                          const float* __restrict__ b2, float* __restrict__ out, int N)
{
    int i = blockIdx.x * 256 + threadIdx.x;
    if (i >= N) return;
    float di = dinv[i], d2 = di * di;
    float2 h = ((const float2*)h2)[i];
    float o0 = h.x * d2, o1 = h.y * d2;
    int beg = rowptr[i], end = rowptr[i + 1];
    for (int e = beg; e < end; ++e) {
        int2 p = epack[e];
        float w = __int_as_float(p.y);
        float2 v = ((const float2*)h2)[p.x];
        o0 += v.x * w; o1 += v.y * w;
    }
    ((float2*)out)[i] = make_float2(o0 + b2[0], o1 + b2[1]);
}

extern "C" void kernel_launch(void* const* d_in, const int* in_sizes, int n_in,
                              void* d_out, int out_size, void* d_ws, size_t ws_size,
                              hipStream_t stream)
{
    const float* x  = (const float*)d_in[0];
    const int*   ei = (const int*)d_in[1];
    const float* W1 = (const float*)d_in[2];
    const float* b1 = (const float*)d_in[3];
    const float* W2 = (const float*)d_in[4];
    const float* b2 = (const float*)d_in[5];
    float* out = (float*)d_out;

    const int N = in_sizes[0] / D1;
    const int E = in_sizes[1] / 2;
    const int* src = ei;
    const int* dst = ei + E;

    char* w = (char*)d_ws;
    unsigned short* h1  = (unsigned short*)w;  w += (size_t)N * D1 * 2;
    unsigned short* W1t = (unsigned short*)w;  w += (size_t)D1 * D1 * 2;
    float* h2     = (float*)w;                 w += (size_t)N * 2 * 4;
    float* dinv   = (float*)w;                 w += (size_t)N * 4;
    int*   cnt    = (int*)w;                   w += (size_t)N * 4;
    int*   rowptr = (int*)w;                   w += (size_t)(N + 2) * 4;
    int*   bsum   = (int*)w;                   w += 256 * 4;
    int*   boff   = (int*)w;                   w += 256 * 4;
    int2*  epack  = (int2*)w;

    const int nb = (N + 1023) >> 10;

    // CSR build + dinv
    k_zero <<<(N + 255) / 256, 256, 0, stream>>>(cnt, N);
    k_hist <<<(E + 255) / 256, 256, 0, stream>>>(dst, cnt, E);
    k_w1cvt<<<(D1 * D1 + 255) / 256, 256, 0, stream>>>(W1, W1t);
    k_scan1<<<nb, 256, 0, stream>>>(cnt, dinv, rowptr, bsum, N);
    k_scan2<<<1, 256, 0, stream>>>(bsum, boff, nb);
    k_scan3<<<(N + 255) / 256, 256, 0, stream>>>(rowptr, cnt, boff, N, E);
    k_fill <<<(E + 255) / 256, 256, 0, stream>>>(src, dst, dinv, cnt, epack, E);

    // layer 1 GEMM (MFMA bf16)
    k_gemm1<<<(N + BMM - 1) / BMM, 256, 0, stream>>>(x, W1t, h1, N);

    // fused agg1 + relu + bias + GEMM2
    k_agg1_gemm2<<<(N * 32 + 255) / 256, 256, 0, stream>>>(rowptr, epack, dinv, h1, b1, W2, h2, N);

    // layer 2 aggregation
    k_gather2<<<(N + 255) / 256, 256, 0, stream>>>(rowptr, epack, h2, dinv, b2, out, N);
}

// Round 6
// 234.503 us; speedup vs baseline: 7.0832x; 1.1242x over previous
//
#include <hip/hip_runtime.h>
#include <hip/hip_bf16.h>

// GCN 2-layer forward. CSR-pull aggregation, bf16 h1, MFMA GEMM1, fused agg1+GEMM2.
// Round 6: fix h1 row stride in agg (16 uint4 per 128-feature row, was 8).

#define D1 128

typedef __attribute__((ext_vector_type(8))) short short8;
typedef __attribute__((ext_vector_type(4))) float floatx4;

__device__ __forceinline__ unsigned short f2bf(float f) {
    unsigned u = __float_as_uint(f);
    u += 0x7fff + ((u >> 16) & 1);         // RNE to bf16
    return (unsigned short)(u >> 16);
}
__device__ __forceinline__ float bflo(unsigned u) { return __uint_as_float(u << 16); }
__device__ __forceinline__ float bfhi(unsigned u) { return __uint_as_float(u & 0xffff0000u); }

// ---------------- init: zero cnt + convert W1 -> W1^T bf16 ----------------
__global__ void k_init(const float* __restrict__ W1, unsigned short* __restrict__ W1t,
                       int* __restrict__ cnt, int N) {
    int i = blockIdx.x * 256 + threadIdx.x;
    if (i < N) cnt[i] = 0;
    if (i < D1 * D1) {
        int c = i >> 7, k = i & 127;
        W1t[c * D1 + k] = f2bf(W1[k * D1 + c]);
    }
}

__global__ void k_hist(const int* __restrict__ dst, int* __restrict__ cnt, int E) {
    int e = blockIdx.x * 256 + threadIdx.x;
    if (e < E) atomicAdd(&cnt[dst[e]], 1);
}

// scan over 1024/block; also emits dinv = rsqrt(1+deg)
__global__ __launch_bounds__(256) void k_scan1(const int* __restrict__ cnt,
                                               float* __restrict__ dinv,
                                               int* __restrict__ rowptr,
                                               int* __restrict__ bsum, int N) {
    __shared__ int sd[256];
    int t = threadIdx.x, b = blockIdx.x;
    int base = b * 1024 + t * 4;
    int v[4], tsum = 0;
#pragma unroll
    for (int i = 0; i < 4; ++i) {
        v[i] = (base + i < N) ? cnt[base + i] : 0;
        if (base + i < N) dinv[base + i] = rsqrtf(1.0f + (float)v[i]);
        tsum += v[i];
    }
    sd[t] = tsum;
    __syncthreads();
    for (int off = 1; off < 256; off <<= 1) {
        int x = (t >= off) ? sd[t - off] : 0;
        __syncthreads();
        sd[t] += x;
        __syncthreads();
    }
    int run = sd[t] - tsum;
#pragma unroll
    for (int i = 0; i < 4; ++i) {
        if (base + i < N) rowptr[base + i] = run;
        run += v[i];
    }
    if (t == 255) bsum[b] = sd[255];
}

__global__ void k_scan2(const int* __restrict__ bsum, int* __restrict__ boff, int nb) {
    __shared__ int sd[256];
    int t = threadIdx.x;
    int v = (t < nb) ? bsum[t] : 0;
    sd[t] = v;
    __syncthreads();
    for (int off = 1; off < 256; off <<= 1) {
        int x = (t >= off) ? sd[t - off] : 0;
        __syncthreads();
        sd[t] += x;
        __syncthreads();
    }
    if (t < nb) boff[t] = sd[t] - v;
}

__global__ void k_scan3(int* __restrict__ rowptr, int* __restrict__ cursor,
                        const int* __restrict__ boff, int N, int E) {
    int i = blockIdx.x * 256 + threadIdx.x;
    if (i < N) {
        int r = rowptr[i] + boff[i >> 10];
        rowptr[i] = r;
        cursor[i] = r;
    }
    if (i == 0) rowptr[N] = E;
}

__global__ void k_fill(const int* __restrict__ src, const int* __restrict__ dst,
                       const float* __restrict__ dinv, int* __restrict__ cursor,
                       int2* __restrict__ epack, int E) {
    int e = blockIdx.x * 256 + threadIdx.x;
    if (e >= E) return;
    int s = src[e], d = dst[e];
    float w = dinv[s] * dinv[d];
    int pos = atomicAdd(&cursor[d], 1);
    epack[pos] = make_int2(s, __float_as_int(w));
}

// ---------------- GEMM1 (MFMA): h1 = bf16(x) @ bf16(W1), bf16 out ----------------
#define BMM 64
__global__ __launch_bounds__(256) void k_gemm1(
    const float* __restrict__ x, const unsigned short* __restrict__ W1t,
    unsigned short* __restrict__ h1, int N)
{
    __shared__ unsigned short Xs[BMM][136];
    __shared__ unsigned short Ws[D1][136];

    const int t = threadIdx.x;
    const int row0 = blockIdx.x * BMM;

#pragma unroll
    for (int i = 0; i < 8; ++i) {
        int idx = t + 256 * i;
        int r = idx >> 4, c8 = idx & 15;
        short8 v = ((const short8*)W1t)[r * 16 + c8];
        *(short8*)&Ws[r][c8 * 8] = v;
    }
#pragma unroll
    for (int i = 0; i < 4; ++i) {
        int idx = t + 256 * i;
        int r = idx >> 4, c8 = idx & 15;
        int row = row0 + r;
        short8 v8 = (short8)0;
        if (row < N) {
            const float* p = x + (size_t)row * D1 + c8 * 8;
            float4 f0 = *(const float4*)p;
            float4 f1 = *(const float4*)(p + 4);
            v8[0] = (short)f2bf(f0.x); v8[1] = (short)f2bf(f0.y);
            v8[2] = (short)f2bf(f0.z); v8[3] = (short)f2bf(f0.w);
            v8[4] = (short)f2bf(f1.x); v8[5] = (short)f2bf(f1.y);
            v8[6] = (short)f2bf(f1.z); v8[7] = (short)f2bf(f1.w);
        }
        *(short8*)&Xs[r][c8 * 8] = v8;
    }
    __syncthreads();

    const int w = t >> 6;
    const int l = t & 63;
    const int m = l & 15;
    const int q = l >> 4;

    floatx4 acc[8];
#pragma unroll
    for (int c = 0; c < 8; ++c) acc[c] = (floatx4)0.0f;

#pragma unroll
    for (int ks = 0; ks < 4; ++ks) {
        short8 a = *(const short8*)&Xs[16 * w + m][ks * 32 + q * 8];
#pragma unroll
        for (int c = 0; c < 8; ++c) {
            short8 b = *(const short8*)&Ws[c * 16 + m][ks * 32 + q * 8];
            acc[c] = __builtin_amdgcn_mfma_f32_16x16x32_bf16(a, b, acc[c], 0, 0, 0);
        }
    }

#pragma unroll
    for (int c = 0; c < 8; ++c) {
#pragma unroll
        for (int r = 0; r < 4; ++r) {
            int row = row0 + 16 * w + q * 4 + r;
            if (row < N) h1[(size_t)row * D1 + c * 16 + m] = f2bf(acc[c][r]);
        }
    }
}

// ---------------- fused: agg(layer1) + relu + bias + GEMM2 ----------------
// 16 lanes/node, uint4 (8 bf16) per lane; row stride = 16 uint4.
// Edge loop unrolled x2 (int4 epack), two independent accumulator sets for MLP.
__global__ __launch_bounds__(256) void k_agg1_gemm2(
    const int* __restrict__ rowptr, const int2* __restrict__ epack,
    const float* __restrict__ dinv, const unsigned short* __restrict__ h1,
    const float* __restrict__ b1, const float* __restrict__ W2,
    float* __restrict__ h2, int N)
{
    int gid = blockIdx.x * 256 + threadIdx.x;
    int node = gid >> 4;
    if (node >= N) return;
    int lane = gid & 15;

    const uint4* h1v = (const uint4*)h1;   // 16 uint4 per 128-feature row

    float di = dinv[node];
    float d2 = di * di;
    uint4 u = h1v[(size_t)node * 16 + lane];
    float accA[8], accB[8];
    accA[0] = bflo(u.x) * d2; accA[1] = bfhi(u.x) * d2;
    accA[2] = bflo(u.y) * d2; accA[3] = bfhi(u.y) * d2;
    accA[4] = bflo(u.z) * d2; accA[5] = bfhi(u.z) * d2;
    accA[6] = bflo(u.w) * d2; accA[7] = bfhi(u.w) * d2;
#pragma unroll
    for (int j = 0; j < 8; ++j) accB[j] = 0.f;

    int beg = rowptr[node], end = rowptr[node + 1];
    int e = beg;
    if ((e & 1) && e < end) {              // peel to even (16B-aligned int4 loads)
        int2 p = epack[e];
        float w = __int_as_float(p.y);
        uint4 v = h1v[(size_t)p.x * 16 + lane];
        accA[0] += bflo(v.x) * w; accA[1] += bfhi(v.x) * w;
        accA[2] += bflo(v.y) * w; accA[3] += bfhi(v.y) * w;
        accA[4] += bflo(v.z) * w; accA[5] += bfhi(v.z) * w;
        accA[6] += bflo(v.w) * w; accA[7] += bfhi(v.w) * w;
        ++e;
    }
    for (; e + 1 < end; e += 2) {
        int4 pp = *(const int4*)&epack[e];   // 2 edges
        float w0 = __int_as_float(pp.y);
        float w1 = __int_as_float(pp.w);
        uint4 v0 = h1v[(size_t)pp.x * 16 + lane];
        uint4 v1 = h1v[(size_t)pp.z * 16 + lane];
        accA[0] += bflo(v0.x) * w0; accA[1] += bfhi(v0.x) * w0;
        accA[2] += bflo(v0.y) * w0; accA[3] += bfhi(v0.y) * w0;
        accA[4] += bflo(v0.z) * w0; accA[5] += bfhi(v0.z) * w0;
        accA[6] += bflo(v0.w) * w0; accA[7] += bfhi(v0.w) * w0;
        accB[0] += bflo(v1.x) * w1; accB[1] += bfhi(v1.x) * w1;
        accB[2] += bflo(v1.y) * w1; accB[3] += bfhi(v1.y) * w1;
        accB[4] += bflo(v1.z) * w1; accB[5] += bfhi(v1.z) * w1;
        accB[6] += bflo(v1.w) * w1; accB[7] += bfhi(v1.w) * w1;
    }
    if (e < end) {
        int2 p = epack[e];
        float w = __int_as_float(p.y);
        uint4 v = h1v[(size_t)p.x * 16 + lane];
        accB[0] += bflo(v.x) * w; accB[1] += bfhi(v.x) * w;
        accB[2] += bflo(v.y) * w; accB[3] += bfhi(v.y) * w;
        accB[4] += bflo(v.z) * w; accB[5] += bfhi(v.z) * w;
        accB[6] += bflo(v.w) * w; accB[7] += bfhi(v.w) * w;
    }

    // bias + relu; features f = lane*8 + j
    float a[8];
    const float4* b1v = (const float4*)b1;
    float4 bbA = b1v[lane * 2 + 0];
    float4 bbB = b1v[lane * 2 + 1];
    a[0] = fmaxf(accA[0] + accB[0] + bbA.x, 0.f);
    a[1] = fmaxf(accA[1] + accB[1] + bbA.y, 0.f);
    a[2] = fmaxf(accA[2] + accB[2] + bbA.z, 0.f);
    a[3] = fmaxf(accA[3] + accB[3] + bbA.w, 0.f);
    a[4] = fmaxf(accA[4] + accB[4] + bbB.x, 0.f);
    a[5] = fmaxf(accA[5] + accB[5] + bbB.y, 0.f);
    a[6] = fmaxf(accA[6] + accB[6] + bbB.z, 0.f);
    a[7] = fmaxf(accA[7] + accB[7] + bbB.w, 0.f);

    // W2 [128][2]; float4 i covers rows 2i,2i+1 -> lane uses indices lane*4..lane*4+3
    const float4* W2v = (const float4*)W2;
    float p0 = 0.f, p1 = 0.f;
#pragma unroll
    for (int j2 = 0; j2 < 4; ++j2) {
        float4 wv = W2v[lane * 4 + j2];
        p0 += a[j2 * 2] * wv.x + a[j2 * 2 + 1] * wv.z;
        p1 += a[j2 * 2] * wv.y + a[j2 * 2 + 1] * wv.w;
    }

#pragma unroll
    for (int off = 8; off > 0; off >>= 1) {
        p0 += __shfl_xor(p0, off);
        p1 += __shfl_xor(p1, off);
    }
    if (lane == 0) {
        h2[(size_t)node * 2 + 0] = p0;
        h2[(size_t)node * 2 + 1] = p1;
    }
}

// ---------------- gather layer 2 (pull), unrolled x2 ----------------
__global__ void k_gather2(const int* __restrict__ rowptr, const int2* __restrict__ epack,
                          const float* __restrict__ h2, const float* __restrict__ dinv,
                          const float* __restrict__ b2, float* __restrict__ out, int N)
{
    int i = blockIdx.x * 256 + threadIdx.x;
    if (i >= N) return;
    const float2* h2v = (const float2*)h2;
    float di = dinv[i], d2 = di * di;
    float2 h = h2v[i];
    float o0a = h.x * d2, o1a = h.y * d2;
    float o0b = 0.f, o1b = 0.f;
    int beg = rowptr[i], end = rowptr[i + 1];
    int e = beg;
    if ((e & 1) && e < end) {
        int2 p = epack[e];
        float w = __int_as_float(p.y);
        float2 v = h2v[p.x];
        o0a += v.x * w; o1a += v.y * w;
        ++e;
    }
    for (; e + 1 < end; e += 2) {
        int4 pp = *(const int4*)&epack[e];
        float w0 = __int_as_float(pp.y);
        float w1 = __int_as_float(pp.w);
        float2 va = h2v[pp.x];
        float2 vb = h2v[pp.z];
        o0a += va.x * w0; o1a += va.y * w0;
        o0b += vb.x * w1; o1b += vb.y * w1;
    }
    if (e < end) {
        int2 p = epack[e];
        float w = __int_as_float(p.y);
        float2 v = h2v[p.x];
        o0b += v.x * w; o1b += v.y * w;
    }
    ((float2*)out)[i] = make_float2(o0a + o0b + b2[0], o1a + o1b + b2[1]);
}

extern "C" void kernel_launch(void* const* d_in, const int* in_sizes, int n_in,
                              void* d_out, int out_size, void* d_ws, size_t ws_size,
                              hipStream_t stream)
{
    const float* x  = (const float*)d_in[0];
    const int*   ei = (const int*)d_in[1];
    const float* W1 = (const float*)d_in[2];
    const float* b1 = (const float*)d_in[3];
    const float* W2 = (const float*)d_in[4];
    const float* b2 = (const float*)d_in[5];
    float* out = (float*)d_out;

    const int N = in_sizes[0] / D1;
    const int E = in_sizes[1] / 2;
    const int* src = ei;
    const int* dst = ei + E;

    char* w = (char*)d_ws;
    auto alloc = [&](size_t bytes) -> char* {
        char* r = w;
        w += (bytes + 15) & ~(size_t)15;   // keep every region 16B-aligned
        return r;
    };
    unsigned short* h1  = (unsigned short*)alloc((size_t)N * D1 * 2);
    unsigned short* W1t = (unsigned short*)alloc((size_t)D1 * D1 * 2);
    float* h2     = (float*)alloc((size_t)N * 2 * 4);
    float* dinv   = (float*)alloc((size_t)N * 4);
    int*   cnt    = (int*)alloc((size_t)N * 4);
    int*   rowptr = (int*)alloc((size_t)(N + 4) * 4);
    int*   bsum   = (int*)alloc(256 * 4);
    int*   boff   = (int*)alloc(256 * 4);
    int2*  epack  = (int2*)alloc((size_t)E * 8);

    const int nb = (N + 1023) >> 10;

    // CSR build + dinv (+ W1 transpose/convert folded into init)
    k_init <<<(N + 255) / 256, 256, 0, stream>>>(W1, W1t, cnt, N);
    k_hist <<<(E + 255) / 256, 256, 0, stream>>>(dst, cnt, E);
    k_scan1<<<nb, 256, 0, stream>>>(cnt, dinv, rowptr, bsum, N);
    k_scan2<<<1, 256, 0, stream>>>(bsum, boff, nb);
    k_scan3<<<(N + 255) / 256, 256, 0, stream>>>(rowptr, cnt, boff, N, E);
    k_fill <<<(E + 255) / 256, 256, 0, stream>>>(src, dst, dinv, cnt, epack, E);

    // layer 1 GEMM (MFMA bf16)
    k_gemm1<<<(N + BMM - 1) / BMM, 256, 0, stream>>>(x, W1t, h1, N);

    // fused agg1 + relu + bias + GEMM2 (16 lanes per node)
    k_agg1_gemm2<<<(N * 16 + 255) / 256, 256, 0, stream>>>(rowptr, epack, dinv, h1, b1, W2, h2, N);

    // layer 2 aggregation
    k_gather2<<<(N + 255) / 256, 256, 0, stream>>>(rowptr, epack, h2, dinv, b2, out, N);
}